// Round 1
// baseline (257.524 us; speedup 1.0000x reference)
//
#include <hip/hip_runtime.h>
#include <hip/hip_bf16.h>

// Conv2d 3x3 s1 p1, NCHW/OIHW fp32 -> fp32, via bf16 implicit GEMM MFMA.
// N=32 C=128 H=W=56 K=256.

#define C_IN   128
#define K_OUT  256
#define HW     56
#define IMG    (HW*HW)        // 3136
#define NBATCH 32
#define SPATIAL (NBATCH*IMG)  // 100352 = 392*256

typedef __bf16 bf16x8 __attribute__((ext_vector_type(8)));
typedef float  f32x4  __attribute__((ext_vector_type(4)));
typedef unsigned int u32x4 __attribute__((ext_vector_type(4)));

__device__ inline unsigned short f2bf(float f) {
    unsigned int u = __builtin_bit_cast(unsigned int, f);
    u += ((u >> 16) & 1u) + 0x7FFFu;   // RNE
    return (unsigned short)(u >> 16);
}

// ---- prep A: NCHW fp32 -> NHWC bf16 (dst[((n*56+y)*56+x)*128 + c]) ----
__global__ void prep_input(const float* __restrict__ inp,
                           unsigned short* __restrict__ dst) {
    __shared__ unsigned short tile[HW * C_IN];   // [x][c], 14336 B
    int n = blockIdx.x / HW, y = blockIdx.x % HW;
    const float* src = inp + (n * C_IN) * IMG + y * HW;
    for (int i = threadIdx.x; i < HW * C_IN; i += blockDim.x) {
        int c = i / HW, x = i - c * HW;          // read coalesced along x
        tile[x * C_IN + c] = f2bf(src[c * IMG + x]);
    }
    __syncthreads();
    unsigned short* d = dst + blockIdx.x * (HW * C_IN);
    for (int i = threadIdx.x; i < HW * C_IN; i += blockDim.x)
        d[i] = tile[i];                           // write coalesced along c
}

// ---- prep B: OIHW fp32 -> [rs][ko][c] bf16 ----
__global__ void prep_weights(const float* __restrict__ w,
                             unsigned short* __restrict__ dst) {
    int idx = blockIdx.x * blockDim.x + threadIdx.x;   // grid covers exactly
    int c  = idx & (C_IN - 1);
    int ko = (idx >> 7) & (K_OUT - 1);
    int rs = idx >> 15;
    dst[idx] = f2bf(w[(ko * C_IN + c) * 9 + rs]);
}

// ---- main conv: implicit GEMM, per wave 64 ko x 64 spatial ----
__global__ __launch_bounds__(256) void conv_mfma(
        const unsigned short* __restrict__ In,   // [SPATIAL][128] bf16
        const unsigned short* __restrict__ Wt,   // [9][256][128] bf16
        const float* __restrict__ bias,
        float* __restrict__ out) {
    const int lane = threadIdx.x & 63;
    const int wv   = threadIdx.x >> 6;
    const int ko0  = blockIdx.y * 64;
    const int s_base = blockIdx.x * 256 + wv * 64;

    const int l15 = lane & 15;
    const int lk8 = (lane >> 4) * 8;

    int ni[4], sp[4], yy[4], xx[4];
#pragma unroll
    for (int n = 0; n < 4; ++n) {
        int p = s_base + n * 16 + l15;
        ni[n] = p / IMG;
        int rem = p - ni[n] * IMG;
        yy[n] = rem / HW;
        xx[n] = rem - yy[n] * HW;
        sp[n] = rem;
    }

    f32x4 acc[4][4];
#pragma unroll
    for (int m = 0; m < 4; ++m)
#pragma unroll
        for (int n = 0; n < 4; ++n) acc[m][n] = (f32x4)0.0f;

    const bf16x8 zero = __builtin_bit_cast(bf16x8, (u32x4)0u);
    const unsigned short* wbase = Wt + (ko0 + l15) * C_IN + lk8;

    for (int rs = 0; rs < 9; ++rs) {
        const int r = rs / 3, s = rs - 3 * r;
        int ioff[4]; bool val[4];
#pragma unroll
        for (int n = 0; n < 4; ++n) {
            int iy = yy[n] + r - 1, ix = xx[n] + s - 1;
            val[n]  = ((unsigned)iy < HW) & ((unsigned)ix < HW);
            ioff[n] = (ni[n] * IMG + iy * HW + ix) * C_IN + lk8;
        }
        const unsigned short* wrs = wbase + rs * (K_OUT * C_IN);
#pragma unroll
        for (int c0 = 0; c0 < C_IN; c0 += 32) {
            bf16x8 a[4], b[4];
#pragma unroll
            for (int m = 0; m < 4; ++m)
                a[m] = *(const bf16x8*)(wrs + m * 16 * C_IN + c0);
#pragma unroll
            for (int n = 0; n < 4; ++n)
                b[n] = val[n] ? *(const bf16x8*)(In + ioff[n] + c0) : zero;
#pragma unroll
            for (int m = 0; m < 4; ++m)
#pragma unroll
                for (int n = 0; n < 4; ++n)
                    acc[m][n] = __builtin_amdgcn_mfma_f32_16x16x32_bf16(
                        a[m], b[n], acc[m][n], 0, 0, 0);
        }
    }

    // epilogue: D[row=ko_local=(lane>>4)*4+j][col=spatial=l15]
    const int jrow = (lane >> 4) * 4;
#pragma unroll
    for (int m = 0; m < 4; ++m) {
        int kb = ko0 + m * 16 + jrow;
        f32x4 bs = *(const f32x4*)(bias + kb);
#pragma unroll
        for (int n = 0; n < 4; ++n) {
#pragma unroll
            for (int j = 0; j < 4; ++j)
                out[(ni[n] * K_OUT + kb + j) * IMG + sp[n]] = acc[m][n][j] + bs[j];
        }
    }
}

// ---- fallback (only if ws too small): naive fp32 direct conv ----
__global__ void conv_naive(const float* __restrict__ inp,
                           const float* __restrict__ ker,
                           const float* __restrict__ bias,
                           float* __restrict__ out, int total) {
    int o = blockIdx.x * blockDim.x + threadIdx.x;
    if (o >= total) return;
    int x = o % HW, y = (o / HW) % HW, ko = (o / IMG) % K_OUT, n = o / (IMG * K_OUT);
    float acc = bias[ko];
    for (int c = 0; c < C_IN; ++c)
        for (int r = 0; r < 3; ++r) {
            int iy = y + r - 1; if ((unsigned)iy >= HW) continue;
            for (int s = 0; s < 3; ++s) {
                int ix = x + s - 1; if ((unsigned)ix >= HW) continue;
                acc += inp[((n * C_IN + c) * HW + iy) * HW + ix]
                     * ker[((ko * C_IN + c) * 3 + r) * 3 + s];
            }
        }
    out[o] = acc;
}

extern "C" void kernel_launch(void* const* d_in, const int* in_sizes, int n_in,
                              void* d_out, int out_size, void* d_ws, size_t ws_size,
                              hipStream_t stream) {
    const float* inp  = (const float*)d_in[0];
    const float* ker  = (const float*)d_in[1];
    const float* bias = (const float*)d_in[2];
    float* out = (float*)d_out;

    const size_t need = (size_t)SPATIAL * C_IN * 2 + (size_t)9 * K_OUT * C_IN * 2;
    if (ws_size < need) {
        int total = NBATCH * K_OUT * IMG;
        conv_naive<<<(total + 255) / 256, 256, 0, stream>>>(inp, ker, bias, out, total);
        return;
    }

    unsigned short* inb = (unsigned short*)d_ws;
    unsigned short* wtb = inb + (size_t)SPATIAL * C_IN;

    prep_input<<<NBATCH * HW, 256, 0, stream>>>(inp, inb);
    prep_weights<<<(9 * K_OUT * C_IN) / 256, 256, 0, stream>>>(ker, wtb);

    dim3 grid(SPATIAL / 256, K_OUT / 64);
    conv_mfma<<<grid, 256, 0, stream>>>(inb, wtb, bias, out);
}

// Round 2
// 96.563 us; speedup vs baseline: 2.6669x; 2.6669x over previous
//
#include <hip/hip_runtime.h>
#include <hip/hip_bf16.h>
#include <stdint.h>

// Conv2d 3x3 s1 p1, NCHW/OIHW fp32 -> fp32. bf16 implicit GEMM, m97 structure:
// padded-NHWC input in ws, weights [ko][rs*c], 128x128 tile, BK=64,
// global_load_lds w/ pre-swizzled source + XOR-swizzled ds_read_b128.

#define C_IN   128
#define K_OUT  256
#define HW     56
#define IMG    3136
#define NBATCH 32
#define SPATIAL 100352      // 32*3136 = 784*128
#define PW     58           // padded width/height
#define PADTOT (NBATCH*PW*PW*C_IN)   // 13778944 elements
#define KTOT   1152         // 9*128

typedef __bf16 bf16x8 __attribute__((ext_vector_type(8)));
typedef float  f32x4  __attribute__((ext_vector_type(4)));

__device__ inline unsigned short f2bf(float f) {
    unsigned int u = __builtin_bit_cast(unsigned int, f);
    u += ((u >> 16) & 1u) + 0x7FFFu;   // RNE
    return (unsigned short)(u >> 16);
}

__device__ __forceinline__ void gl2lds16(const unsigned short* g, unsigned short* l) {
    __builtin_amdgcn_global_load_lds(
        (const __attribute__((address_space(1))) unsigned int*)g,
        (__attribute__((address_space(3))) unsigned int*)l, 16, 0, 0);
}

// ---- prep A: NCHW fp32 -> padded NHWC bf16 [n][py 0..57][px 0..57][c] ----
__global__ void prep_input(const float* __restrict__ inp,
                           unsigned short* __restrict__ dst) {
    __shared__ unsigned short tile[C_IN * 57];   // [c][x], stride 57 kills conflicts
    int n = blockIdx.x / PW, py = blockIdx.x % PW;
    unsigned short* d = dst + (size_t)blockIdx.x * (PW * C_IN);
    if (py == 0 || py == PW - 1) {
        for (int i = threadIdx.x; i < PW * C_IN; i += 256) d[i] = 0;
        return;
    }
    const float* src = inp + (size_t)n * C_IN * IMG + (py - 1) * HW;
    for (int i = threadIdx.x; i < C_IN * HW; i += 256) {
        int c = i / HW, x = i - c * HW;          // coalesced read along x
        tile[c * 57 + x] = f2bf(src[c * IMG + x]);
    }
    __syncthreads();
    for (int i = threadIdx.x; i < PW * C_IN; i += 256) {
        int px = i >> 7, c = i & 127;
        unsigned short v = 0;
        if (px >= 1 && px <= HW) v = tile[c * 57 + (px - 1)];
        d[i] = v;                                 // coalesced write along c
    }
}

// ---- prep B: OIHW fp32 -> [ko][rs][c] bf16 (plain 256x1152 row-major) ----
__global__ void prep_weights(const float* __restrict__ w,
                             unsigned short* __restrict__ dst) {
    int idx = blockIdx.x * 256 + threadIdx.x;
    int ko = idx / KTOT, rem = idx - ko * KTOT;
    int rs = rem >> 7, c = rem & 127;
    dst[idx] = f2bf(w[(ko * C_IN + c) * 9 + rs]);
}

// ---- main conv: 128(ko) x 128(px) tile, BK=64, 4 waves, LDS-staged ----
__global__ __launch_bounds__(256) void conv_mfma(
        const unsigned short* __restrict__ In,   // padded NHWC bf16
        const unsigned short* __restrict__ Wt,   // [256][1152] bf16
        const float* __restrict__ bias,
        float* __restrict__ out) {
    __shared__ unsigned short smem[16384];       // A bytes [0,16K), B [16K,32K)

    const int tid = threadIdx.x;
    const int lane = tid & 63, w = tid >> 6;
    const int wr = w >> 1, wc = w & 1;           // wave quadrant: ko-half, px-half
    const int l15 = lane & 15, lk = lane >> 4;
    const int lr = lane >> 3, lj = lane & 7;
    const int jd = lj ^ lr;                      // pre-swizzled source chunk

    const int pblk0 = blockIdx.x * 128;
    const int ko0   = blockIdx.y * 128;

    // per-lane staging constants (fixed across K loop)
    int eA[4]; int pbq[4];
#pragma unroll
    for (int qi = 0; qi < 4; ++qi) {
        int row = 32 * w + 8 * qi + lr;          // tile row this lane stages
        eA[qi] = (ko0 + row) * KTOT + jd * 8;
        int p = pblk0 + row;
        int n = p / IMG; int rem = p - n * IMG;
        int y = rem / HW; int x = rem - y * HW;
        pbq[qi] = ((n * PW + y) * PW + x) * C_IN + jd * 8;
    }

    f32x4 acc[4][4];
#pragma unroll
    for (int m = 0; m < 4; ++m)
#pragma unroll
        for (int n = 0; n < 4; ++n) acc[m][n] = (f32x4)0.0f;

    const int jx0   = lk ^ (l15 & 7);            // read-side swizzle base
    const int aBase = (wr * 64 + l15) * 128;     // byte offsets in LDS
    const int bBase = 16384 + (wc * 64 + l15) * 128;
    const char* sm = (const char*)smem;

#pragma unroll
    for (int kt = 0; kt < 18; ++kt) {
        const int rs = kt >> 1;
        const int r = rs / 3, s = rs - 3 * (rs / 3);
        const int goff = (r * PW + s) * C_IN + (kt & 1) * 64;  // compile-time
        // stage A (weights) and B (input) tiles: 4 x 1KB chunks each per wave
#pragma unroll
        for (int qi = 0; qi < 4; ++qi)
            gl2lds16(Wt + eA[qi] + kt * 64, &smem[(4 * w + qi) * 512]);
#pragma unroll
        for (int qi = 0; qi < 4; ++qi)
            gl2lds16(In + pbq[qi] + goff, &smem[8192 + (4 * w + qi) * 512]);
        __syncthreads();
#pragma unroll
        for (int ks = 0; ks < 2; ++ks) {
            const int jo = (jx0 ^ (ks ? 4 : 0)) * 16;
            bf16x8 a[4], b[4];
#pragma unroll
            for (int m = 0; m < 4; ++m)
                a[m] = *(const bf16x8*)(sm + aBase + m * 2048 + jo);
#pragma unroll
            for (int n = 0; n < 4; ++n)
                b[n] = *(const bf16x8*)(sm + bBase + n * 2048 + jo);
#pragma unroll
            for (int m = 0; m < 4; ++m)
#pragma unroll
                for (int n = 0; n < 4; ++n)
                    acc[m][n] = __builtin_amdgcn_mfma_f32_16x16x32_bf16(
                        a[m], b[n], acc[m][n], 0, 0, 0);
        }
        __syncthreads();
    }

    // epilogue: D col = l15 (pixel), row = lk*4 + j (ko)
    const int jrow = lk * 4;
#pragma unroll
    for (int m = 0; m < 4; ++m) {
        int kb = ko0 + wr * 64 + m * 16 + jrow;
        f32x4 bs = *(const f32x4*)(bias + kb);
#pragma unroll
        for (int nf = 0; nf < 4; ++nf) {
            int p = pblk0 + wc * 64 + nf * 16 + l15;
            int ni = p / IMG; int spi = p - ni * IMG;
            float* ob = out + (size_t)(ni * K_OUT + kb) * IMG + spi;
#pragma unroll
            for (int j = 0; j < 4; ++j)
                ob[j * IMG] = acc[m][nf][j] + bs[j];
        }
    }
}

// ---- fallback (only if ws too small): naive fp32 direct conv ----
__global__ void conv_naive(const float* __restrict__ inp,
                           const float* __restrict__ ker,
                           const float* __restrict__ bias,
                           float* __restrict__ out, int total) {
    int o = blockIdx.x * blockDim.x + threadIdx.x;
    if (o >= total) return;
    int x = o % HW, y = (o / HW) % HW, ko = (o / IMG) % K_OUT, n = o / (IMG * K_OUT);
    float acc = bias[ko];
    for (int c = 0; c < C_IN; ++c)
        for (int r = 0; r < 3; ++r) {
            int iy = y + r - 1; if ((unsigned)iy >= HW) continue;
            for (int s = 0; s < 3; ++s) {
                int ix = x + s - 1; if ((unsigned)ix >= HW) continue;
                acc += inp[((n * C_IN + c) * HW + iy) * HW + ix]
                     * ker[((ko * C_IN + c) * 3 + r) * 3 + s];
            }
        }
    out[o] = acc;
}

extern "C" void kernel_launch(void* const* d_in, const int* in_sizes, int n_in,
                              void* d_out, int out_size, void* d_ws, size_t ws_size,
                              hipStream_t stream) {
    const float* inp  = (const float*)d_in[0];
    const float* ker  = (const float*)d_in[1];
    const float* bias = (const float*)d_in[2];
    float* out = (float*)d_out;

    const size_t need = (size_t)PADTOT * 2 + (size_t)K_OUT * KTOT * 2;
    if (ws_size < need) {
        int total = NBATCH * K_OUT * IMG;
        conv_naive<<<(total + 255) / 256, 256, 0, stream>>>(inp, ker, bias, out, total);
        return;
    }

    unsigned short* inb = (unsigned short*)d_ws;
    unsigned short* wtb = inb + (size_t)PADTOT;

    prep_input<<<NBATCH * PW, 256, 0, stream>>>(inp, inb);
    prep_weights<<<(K_OUT * KTOT) / 256, 256, 0, stream>>>(ker, wtb);

    dim3 grid(SPATIAL / 128, K_OUT / 128);
    conv_mfma<<<grid, 256, 0, stream>>>(inb, wtb, bias, out);
}

// Round 3
// 91.068 us; speedup vs baseline: 2.8278x; 1.0603x over previous
//
#include <hip/hip_runtime.h>
#include <hip/hip_bf16.h>

// Conv2d 3x3 s1 p1, NCHW/OIHW fp32 -> fp32. bf16 implicit GEMM with
// conv-aware LDS reuse: input rows staged once per c-quarter, all 9 taps
// run from LDS. 256ko x 224px blocks, 12 phases, counted vmcnt, setprio.

#define C_IN   128
#define K_OUT  256
#define HW     56
#define IMG    3136
#define NBATCH 32
#define SPATIAL 100352
#define PW     58
#define PADTOT (NBATCH*PW*PW*C_IN)
#define KTOT   1152

typedef __bf16 bf16x8 __attribute__((ext_vector_type(8)));
typedef float  f32x4  __attribute__((ext_vector_type(4)));
typedef unsigned short ushort8 __attribute__((ext_vector_type(8)));

__device__ inline unsigned short f2bf(float f) {
    unsigned int u = __builtin_bit_cast(unsigned int, f);
    u += ((u >> 16) & 1u) + 0x7FFFu;   // RNE
    return (unsigned short)(u >> 16);
}

__device__ __forceinline__ void gl2lds16(const unsigned short* g, unsigned short* l) {
    __builtin_amdgcn_global_load_lds(
        (const __attribute__((address_space(1))) unsigned int*)g,
        (__attribute__((address_space(3))) unsigned int*)l, 16, 0, 0);
}

// ---- prep A: NCHW fp32 -> padded NHWC bf16 [n][py 0..57][px 0..57][c] ----
__global__ void prep_input(const float* __restrict__ inp,
                           unsigned short* __restrict__ dst) {
    __shared__ unsigned short tile[C_IN * 57];   // [c][x], stride 57
    int n = blockIdx.x / PW, py = blockIdx.x % PW;
    ushort8* d8 = (ushort8*)(dst + (size_t)blockIdx.x * (PW * C_IN));
    if (py == 0 || py == PW - 1) {
        for (int i = threadIdx.x; i < PW * C_IN / 8; i += 256) d8[i] = (ushort8)0;
        return;
    }
    const float* src = inp + (size_t)n * C_IN * IMG + (py - 1) * HW;
    for (int i = threadIdx.x; i < C_IN * HW; i += 256) {
        int c = i / HW, x = i - c * HW;          // coalesced read along x
        tile[c * 57 + x] = f2bf(src[c * IMG + x]);
    }
    __syncthreads();
    for (int i = threadIdx.x; i < PW * C_IN / 8; i += 256) {   // 928 chunks
        int px = i >> 4, c0 = (i & 15) * 8;
        ushort8 v = (ushort8)0;
        if (px >= 1 && px <= HW) {
#pragma unroll
            for (int e = 0; e < 8; ++e) v[e] = tile[(c0 + e) * 57 + (px - 1)];
        }
        d8[i] = v;
    }
}

// ---- prep B: OIHW fp32 -> [ko][rs][c] bf16 ----
__global__ void prep_weights(const float* __restrict__ w,
                             unsigned short* __restrict__ dst) {
    int idx = blockIdx.x * 256 + threadIdx.x;
    int ko = idx / KTOT, rem = idx - ko * KTOT;
    int rs = rem >> 7, c = rem & 127;
    dst[idx] = f2bf(w[(ko * C_IN + c) * 9 + rs]);
}

// ---- main conv ----
// LDS map (ushort idx): wslot0 [0,24576) wslot1 [24576,49152)
//                       islot0 [49152,61440) islot1 [61440,73728)
// wslot: [3 s][256 ko][32 c]  islot: [6 t][58 X][32 c] (+pad to 1536 chunks)
__global__ __launch_bounds__(512, 2) void conv_mfma(
        const unsigned short* __restrict__ In,
        const unsigned short* __restrict__ Wt,
        const float* __restrict__ bias,
        float* __restrict__ out) {
    __shared__ unsigned short smem[73728];

    const int tid = threadIdx.x;
    const int lane = tid & 63, wv = tid >> 6;
    const int l15 = lane & 15, lk = lane >> 4;
    const int blk = blockIdx.x;
    const int n = blk / 14, rb = (blk % 14) * 4;   // first image row of block

    const int wko = (wv & 3) * 64;                 // wave ko base (local)
    const int wpx = (wv >> 2) * 112;               // wave px base (local)
    const int albase = l15 * 64 + lk * 16;         // A lane byte offset

    int rowoff[7];                                 // B lane byte offsets
#pragma unroll
    for (int nf = 0; nf < 7; ++nf) {
        int p = wpx + nf * 16 + l15;               // local pixel 0..223
        int yl = p / 56, x = p - yl * 56;
        rowoff[nf] = (yl * 58 + x) * 64 + lk * 16;
    }

    f32x4 acc[4][7];
#pragma unroll
    for (int m = 0; m < 4; ++m)
#pragma unroll
        for (int nf = 0; nf < 7; ++nf) acc[m][nf] = (f32x4)0.0f;

#define STAGE_W(PHN, RN, CQN) do {                                          \
    _Pragma("unroll")                                                       \
    for (int li = 0; li < 6; ++li) {                                        \
        int chunk = li * 512 + tid;                                         \
        int s_ = chunk >> 10, rem_ = chunk & 1023;                          \
        int ko_ = rem_ >> 2, cc_ = rem_ & 3;                                \
        gl2lds16(Wt + ko_ * KTOT + ((RN) * 3 + s_) * 128 + (CQN) * 32 + cc_ * 8, \
                 &smem[((PHN) & 1) * 24576 + chunk * 8]);                   \
    } } while (0)

#define STAGE_I(CQN, R_) do {                                               \
    int chunk = (R_) * 512 + tid;                                           \
    int ch2 = chunk < 1392 ? chunk : 0;                                     \
    int t_ = ch2 / 232, rem_ = ch2 - t_ * 232;                              \
    int X_ = rem_ >> 2, cc_ = rem_ & 3;                                     \
    gl2lds16(In + (((n * 58 + rb + t_) * 58 + X_) * 128) + (CQN) * 32 + cc_ * 8, \
             &smem[49152 + ((CQN) & 1) * 12288 + chunk * 8]);               \
} while (0)

    // prologue: weights for phase 0, input for c-quarter 0
    STAGE_W(0, 0, 0);
    STAGE_I(0, 0); STAGE_I(0, 1); STAGE_I(0, 2);

#define PHASE(PH) do {                                                      \
    constexpr int cq_ = (PH) / 3, r_ = (PH) % 3;                            \
    if ((PH) < 11) { STAGE_W((PH) + 1, ((PH) + 1) % 3, ((PH) + 1) / 3); }   \
    if (cq_ < 3)   { STAGE_I(cq_ + 1, r_); }                                \
    asm volatile("s_waitcnt vmcnt(%0)"                                      \
                 :: "i"((PH) < 9 ? 7 : ((PH) < 11 ? 6 : 0)) : "memory");    \
    __builtin_amdgcn_s_barrier();                                           \
    { const char* wb = (const char*)smem + ((PH) & 1) * 49152;              \
      const char* ib = (const char*)smem + 98304 + (cq_ & 1) * 24576;       \
      __builtin_amdgcn_s_setprio(1);                                        \
      _Pragma("unroll")                                                     \
      for (int s = 0; s < 3; ++s) {                                         \
          bf16x8 a[4], b[7];                                                \
          _Pragma("unroll")                                                 \
          for (int m = 0; m < 4; ++m)                                       \
              a[m] = *(const bf16x8*)(wb + s * 16384 + (wko + m * 16) * 64 + albase); \
          _Pragma("unroll")                                                 \
          for (int nf = 0; nf < 7; ++nf)                                    \
              b[nf] = *(const bf16x8*)(ib + rowoff[nf] + (r_ * 58 + s) * 64); \
          _Pragma("unroll")                                                 \
          for (int m = 0; m < 4; ++m)                                       \
              _Pragma("unroll")                                             \
              for (int nf = 0; nf < 7; ++nf)                                \
                  acc[m][nf] = __builtin_amdgcn_mfma_f32_16x16x32_bf16(     \
                      a[m], b[nf], acc[m][nf], 0, 0, 0);                    \
      }                                                                     \
      __builtin_amdgcn_s_setprio(0);                                        \
    }                                                                       \
    __builtin_amdgcn_s_barrier();                                           \
} while (0)

    PHASE(0);  PHASE(1);  PHASE(2);  PHASE(3);
    PHASE(4);  PHASE(5);  PHASE(6);  PHASE(7);
    PHASE(8);  PHASE(9);  PHASE(10); PHASE(11);

#undef PHASE
#undef STAGE_I
#undef STAGE_W

    // epilogue: D col = l15 (pixel), row = lk*4 + j (ko)
    const int sp0 = rb * 56 + wpx;                 // block pixel base in image
#pragma unroll
    for (int m = 0; m < 4; ++m) {
        int kb = wko + m * 16 + lk * 4;            // absolute ko (block covers all 256)
        f32x4 bs = *(const f32x4*)(bias + kb);
#pragma unroll
        for (int nf = 0; nf < 7; ++nf) {
            float* ob = out + ((size_t)(n * K_OUT + kb) * IMG) + sp0 + nf * 16 + l15;
#pragma unroll
            for (int j = 0; j < 4; ++j)
                ob[(size_t)j * IMG] = acc[m][nf][j] + bs[j];
        }
    }
}

// ---- fallback (only if ws too small): naive fp32 direct conv ----
__global__ void conv_naive(const float* __restrict__ inp,
                           const float* __restrict__ ker,
                           const float* __restrict__ bias,
                           float* __restrict__ out, int total) {
    int o = blockIdx.x * blockDim.x + threadIdx.x;
    if (o >= total) return;
    int x = o % HW, y = (o / HW) % HW, ko = (o / IMG) % K_OUT, n = o / (IMG * K_OUT);
    float acc = bias[ko];
    for (int c = 0; c < C_IN; ++c)
        for (int r = 0; r < 3; ++r) {
            int iy = y + r - 1; if ((unsigned)iy >= HW) continue;
            for (int s = 0; s < 3; ++s) {
                int ix = x + s - 1; if ((unsigned)ix >= HW) continue;
                acc += inp[((n * C_IN + c) * HW + iy) * HW + ix]
                     * ker[((ko * C_IN + c) * 3 + r) * 3 + s];
            }
        }
    out[o] = acc;
}

extern "C" void kernel_launch(void* const* d_in, const int* in_sizes, int n_in,
                              void* d_out, int out_size, void* d_ws, size_t ws_size,
                              hipStream_t stream) {
    const float* inp  = (const float*)d_in[0];
    const float* ker  = (const float*)d_in[1];
    const float* bias = (const float*)d_in[2];
    float* out = (float*)d_out;

    const size_t need = (size_t)PADTOT * 2 + (size_t)K_OUT * KTOT * 2;
    if (ws_size < need) {
        int total = NBATCH * K_OUT * IMG;
        conv_naive<<<(total + 255) / 256, 256, 0, stream>>>(inp, ker, bias, out, total);
        return;
    }

    unsigned short* inb = (unsigned short*)d_ws;
    unsigned short* wtb = inb + (size_t)PADTOT;

    prep_input<<<NBATCH * PW, 256, 0, stream>>>(inp, inb);
    prep_weights<<<(K_OUT * KTOT) / 256, 256, 0, stream>>>(ker, wtb);

    conv_mfma<<<448, 512, 0, stream>>>(inb, wtb, bias, out);
}